// Round 4
// baseline (401.368 us; speedup 1.0000x reference)
//
#include <hip/hip_runtime.h>
#include <cmath>

// Problem constants (from reference):
//   F=26 features, B=16384 batch, V=100000 vocab/table, D=32 embed dim, H=13
constexpr int F = 26;
constexpr int B = 16384;
constexpr int V = 100000;
constexpr int D = 32;
constexpr int H = 13;

// Native clang vector type for __builtin_nontemporal_store (the builtin
// rejects HIP_vector_type<float,4>; this ext_vector is layout-identical).
typedef float nfloat4 __attribute__((ext_vector_type(4)));

// ---------------------------------------------------------------------------
// Single fused kernel.
//
// Prologue (per block, redundant but identical across blocks):
//   scale[F] = sigmoid(w2 @ relu(w1 @ se_last)),
//   se_last[f] = mean_d tables[f, x[f, B-1], d].
// The reference uses only gate[-1], so the SE-net collapses to 26 row-means
// + a 26->13->26 MLP. Every block recomputes it from L2/L3-cached data
// (26 x dwords + 26 table rows = 3.3 KB), eliminating the separate
// <<<1,64>>> kernel and its ~10us launch/serialization overhead.
//
// Main phase: out[b, f*D+d] = tables[f, x[f,b], d] * scale[f]
//   ITEMS=4 float4s per thread from 4 disjoint slices of the flat index
//   space: all 4 x-loads issued back-to-back, then all 4 table-row loads
//   (4 KB in flight per wave), then scaled non-temporal stores (out is
//   write-once; keep L2/L3 residency for the gather stream).
//   Flat g in [0, B*F*D/4): b = g/208, r = g%208, f = r>>3, d4 = r&7.
//   Each 8-lane group reads one contiguous 128B-aligned table row; stores
//   are fully coalesced 16B/lane.
// ---------------------------------------------------------------------------
constexpr int F4_PER_B = F * D / 4;          // 208 float4 per batch row
constexpr int TOTAL_F4 = B * F4_PER_B;       // 3,407,872
constexpr int ITEMS    = 4;
constexpr int THREADS  = 256;
constexpr int SLICE    = TOTAL_F4 / ITEMS;   // 851,968 (exact)
constexpr int GRID     = SLICE / THREADS;    // 3,328 blocks (exact)

__global__ __launch_bounds__(256) void fused_gather_se_kernel(
        const int* __restrict__ x,
        const float4* __restrict__ tables4,
        const float* __restrict__ w1,
        const float* __restrict__ w2,
        nfloat4* __restrict__ out4) {
    __shared__ float s_part[F * 8];   // 208 partial row sums
    __shared__ float s_se[F];
    __shared__ float s_h[H];
    __shared__ float s_scale[F];

    const int t = threadIdx.x;

    // ---- Prologue: compute scale[F] (identical in every block) ----
    if (t < F * 8) {
        const int f  = t >> 3;
        const int d4 = t & 7;
        const int idx = x[f * B + (B - 1)];
        float4 v = tables4[(size_t)f * (V * D / 4) + (size_t)idx * (D / 4) + d4];
        s_part[t] = v.x + v.y + v.z + v.w;
    }
    __syncthreads();
    if (t < F) {
        float s = 0.0f;
#pragma unroll
        for (int j = 0; j < 8; ++j) s += s_part[t * 8 + j];
        s_se[t] = s * (1.0f / (float)D);
    }
    __syncthreads();
    if (t < H) {
        float a = 0.0f;
#pragma unroll
        for (int f = 0; f < F; ++f) a += w1[t * F + f] * s_se[f];
        s_h[t] = a > 0.0f ? a : 0.0f;  // relu
    }
    __syncthreads();
    if (t < F) {
        float a = 0.0f;
#pragma unroll
        for (int j = 0; j < H; ++j) a += w2[t * H + j] * s_h[j];
        s_scale[t] = 1.0f / (1.0f + expf(-a));  // sigmoid
    }
    __syncthreads();

    // ---- Main gather+scale, ITEMS independent float4s per thread ----
    const int tid = blockIdx.x * THREADS + t;

    int f[ITEMS], d4[ITEMS], bb[ITEMS];
#pragma unroll
    for (int k = 0; k < ITEMS; ++k) {
        const int g = tid + k * SLICE;
        const int b = g / F4_PER_B;          // magic-mul division
        const int r = g - b * F4_PER_B;
        f[k]  = r >> 3;
        d4[k] = r & 7;
        bb[k] = b;
    }

    // Phase 1: all index loads (independent; 8-lane broadcast per row).
    int idx[ITEMS];
#pragma unroll
    for (int k = 0; k < ITEMS; ++k) idx[k] = x[f[k] * B + bb[k]];

    // Phase 2: all table-row loads (independent 16B/lane, 128B/group).
    float4 v[ITEMS];
#pragma unroll
    for (int k = 0; k < ITEMS; ++k)
        v[k] = tables4[(size_t)f[k] * (V * D / 4) + (size_t)idx[k] * (D / 4) + d4[k]];

    // Phase 3: scale from LDS, non-temporal coalesced stores.
#pragma unroll
    for (int k = 0; k < ITEMS; ++k) {
        const float s = s_scale[f[k]];
        nfloat4 w;
        w.x = v[k].x * s; w.y = v[k].y * s;
        w.z = v[k].z * s; w.w = v[k].w * s;
        __builtin_nontemporal_store(w, &out4[tid + (size_t)k * SLICE]);
    }
}

extern "C" void kernel_launch(void* const* d_in, const int* in_sizes, int n_in,
                              void* d_out, int out_size, void* d_ws, size_t ws_size,
                              hipStream_t stream) {
    const int*   x      = (const int*)d_in[0];     // [F, B] int32
    const float* tables = (const float*)d_in[1];   // [F, V, D] fp32
    const float* w1     = (const float*)d_in[2];   // [H, F] fp32
    const float* w2     = (const float*)d_in[3];   // [F, H] fp32
    float*       out    = (float*)d_out;           // [B, F*D] fp32

    fused_gather_se_kernel<<<GRID, THREADS, 0, stream>>>(
        x, (const float4*)tables, w1, w2, (nfloat4*)out);
}

// Round 5
// 399.035 us; speedup vs baseline: 1.0058x; 1.0058x over previous
//
#include <hip/hip_runtime.h>
#include <cmath>

// Problem constants (from reference):
//   F=26 features, B=16384 batch, V=100000 vocab/table, D=32 embed dim, H=13
constexpr int F = 26;
constexpr int B = 16384;
constexpr int V = 100000;
constexpr int D = 32;
constexpr int H = 13;

// Native clang vector type for __builtin_nontemporal_store (the builtin
// rejects HIP_vector_type<float,4>; this ext_vector is layout-identical).
typedef float nfloat4 __attribute__((ext_vector_type(4)));

// ---------------------------------------------------------------------------
// Single fused kernel, F-MAJOR decomposition (round-5 experiment).
//
// Prologue (per block, identical across blocks): scale[F] =
// sigmoid(w2 @ relu(w1 @ se_last)), se_last[f] = mean_d tables[f, x[f,B-1], d].
// Reference uses only gate[-1], so the SE-net collapses to this.
//
// Main phase: each block owns ONE feature f and 128 consecutive batch rows.
//   - all of the block's table reads hit one 12.8 MB table (L2/TLB locality);
//   - XCD-chunked swizzle packs each feature's blocks onto one XCD, so each
//     XCD touches ~3 tables (unique rows/table ~1.9 MB -> duplicate hits
//     land in the XCD-local 4 MB L2 instead of L3);
//   - x-index loads are fully coalesced (32 consecutive dwords per wave);
//   - scale[f] is block-uniform (one LDS broadcast);
//   - writes are 128 B-contiguous chunks at stride 3328 B, non-temporal.
// Layout per thread: lane_d4 = t&7 (float4 within row), row = t>>3 + 32k,
// k = 0..3 (ITEMS=4 -> 4 KB of table reads in flight per wave).
// ---------------------------------------------------------------------------
constexpr int F4_PER_B   = F * D / 4;     // 208 float4 per output batch row
constexpr int THREADS    = 256;
constexpr int ITEMS      = 4;
constexpr int ROWS_PER_BLOCK = THREADS / 8 * ITEMS;  // 128
constexpr int BLOCKS_PER_F   = B / ROWS_PER_BLOCK;   // 128
constexpr int GRID           = F * BLOCKS_PER_F;     // 3328 (divisible by 8)

__global__ __launch_bounds__(256) void fused_gather_se_fmajor(
        const int* __restrict__ x,
        const float4* __restrict__ tables4,
        const float* __restrict__ w1,
        const float* __restrict__ w2,
        nfloat4* __restrict__ out4) {
    __shared__ float s_part[F * 8];   // 208 partial row sums
    __shared__ float s_se[F];
    __shared__ float s_h[H];
    __shared__ float s_scale[F];

    const int t = threadIdx.x;

    // ---- Prologue: compute scale[F] (identical in every block) ----
    if (t < F * 8) {
        const int f  = t >> 3;
        const int d4 = t & 7;
        const int idx = x[f * B + (B - 1)];
        float4 v = tables4[(size_t)f * (V * D / 4) + (size_t)idx * (D / 4) + d4];
        s_part[t] = v.x + v.y + v.z + v.w;
    }
    __syncthreads();
    if (t < F) {
        float s = 0.0f;
#pragma unroll
        for (int j = 0; j < 8; ++j) s += s_part[t * 8 + j];
        s_se[t] = s * (1.0f / (float)D);
    }
    __syncthreads();
    if (t < H) {
        float a = 0.0f;
#pragma unroll
        for (int f = 0; f < F; ++f) a += w1[t * F + f] * s_se[f];
        s_h[t] = a > 0.0f ? a : 0.0f;  // relu
    }
    __syncthreads();
    if (t < F) {
        float a = 0.0f;
#pragma unroll
        for (int j = 0; j < H; ++j) a += w2[t * H + j] * s_h[j];
        s_scale[t] = 1.0f / (1.0f + expf(-a));  // sigmoid
    }
    __syncthreads();

    // ---- F-major block mapping with XCD-chunked swizzle (3328 % 8 == 0,
    // bijective): XCD x gets virtual block ids [x*416, (x+1)*416). ----
    const int bid  = blockIdx.x;
    const int vbid = (bid & 7) * (GRID / 8) + (bid >> 3);
    const int f     = vbid >> 7;            // vbid / BLOCKS_PER_F
    const int bbase = (vbid & 127) << 7;    // (vbid % 128) * ROWS_PER_BLOCK

    const float s   = s_scale[f];           // block-uniform broadcast
    const int lane_d4    = t & 7;           // float4 index within a row
    const int row_in_blk = t >> 3;          // 0..31

    const float4* __restrict__ tbase = tables4 + (size_t)f * (V * D / 4);
    const int*    __restrict__ xf    = x + f * B + bbase;

    // Phase 1: coalesced index loads (32 consecutive dwords per wave-item).
    int idx[ITEMS];
#pragma unroll
    for (int k = 0; k < ITEMS; ++k) idx[k] = xf[row_in_blk + k * 32];

    // Phase 2: table-row loads — all within ONE table (16B/lane, 128B/group).
    float4 v[ITEMS];
#pragma unroll
    for (int k = 0; k < ITEMS; ++k)
        v[k] = tbase[(size_t)idx[k] * (D / 4) + lane_d4];

    // Phase 3: scaled non-temporal stores, 128B-contiguous per 8-lane group.
#pragma unroll
    for (int k = 0; k < ITEMS; ++k) {
        const int b = bbase + row_in_blk + k * 32;
        nfloat4 w;
        w.x = v[k].x * s; w.y = v[k].y * s;
        w.z = v[k].z * s; w.w = v[k].w * s;
        __builtin_nontemporal_store(w, &out4[(size_t)b * F4_PER_B + f * 8 + lane_d4]);
    }
}

extern "C" void kernel_launch(void* const* d_in, const int* in_sizes, int n_in,
                              void* d_out, int out_size, void* d_ws, size_t ws_size,
                              hipStream_t stream) {
    const int*   x      = (const int*)d_in[0];     // [F, B] int32
    const float* tables = (const float*)d_in[1];   // [F, V, D] fp32
    const float* w1     = (const float*)d_in[2];   // [H, F] fp32
    const float* w2     = (const float*)d_in[3];   // [F, H] fp32
    float*       out    = (float*)d_out;           // [B, F*D] fp32

    fused_gather_se_fmajor<<<GRID, THREADS, 0, stream>>>(
        x, (const float4*)tables, w1, w2, (nfloat4*)out);
}